// Round 2
// baseline (3732.015 us; speedup 1.0000x reference)
//
#include <hip/hip_runtime.h>
#include <stdint.h>

// SparseConv3d: B=2, Cin=32, Cout=64, D=64, K=3, 'same' padding, masked output.
// Round 1: fp32 direct conv, correctness first.
//   - mask is int32 (harness maps jnp.bool_ -> int), NOT uint8 (round-0 bug theory #1)
//   - LDS cut to 37.1 KB via 2-phase ci split (round-0 bug theory #2 + occupancy 2->4 blk/CU)
//   - block = (b,z,y), 256 threads = 4 waves; lane = x (full row of 64)
//   - wave w computes co in [16w, 16w+16); weights are wave-uniform -> s_load
//   - fp32 VALU compute floor ~369 us @ 100% VALU (no fp32 MFMA on CDNA4)

#define DD 64
#define CIN 32
#define COUT 64
#define CI_BLK 16

__global__ __launch_bounds__(256, 2)
void sparse_conv3d_f32(const float* __restrict__ x,
                       const int* __restrict__ mask,
                       const float* __restrict__ weight,
                       const float* __restrict__ bias,
                       float* __restrict__ out) {
    __shared__ float lds[9 * CI_BLK * 66];   // 37.1 KB

    const int y = blockIdx.x;
    const int z = blockIdx.y;
    const int b = blockIdx.z;
    const int lane = threadIdx.x & 63;
    const int wave = __builtin_amdgcn_readfirstlane(threadIdx.x >> 6);

    float acc[16];
#pragma unroll
    for (int j = 0; j < 16; ++j) acc[j] = 0.0f;

    const int co0 = wave * 16;
    const float* wbase = weight + (size_t)co0 * (CIN * 27);

    for (int cb = 0; cb < 2; ++cb) {
        if (cb) __syncthreads();   // previous phase's reads must finish before overwrite

        // ---- Stage 9 (z+kz-1, y+ky-1) rows x 16 channels into LDS, x zero-halo ----
        for (int i = wave; i < 9 * CI_BLK; i += 4) {
            const int r    = i >> 4;    // 0..8
            const int ci_l = i & 15;
            const int zz = z + (r / 3) - 1;
            const int yy = y + (r % 3) - 1;
            const int ci = cb * CI_BLK + ci_l;
            float v = 0.0f;
            if (zz >= 0 && zz < DD && yy >= 0 && yy < DD) {
                v = x[((((size_t)b * CIN + ci) * DD + zz) * DD + yy) * DD + lane];
            }
            float* row = &lds[(size_t)i * 66];
            row[1 + lane] = v;
            if (lane == 0) { row[0] = 0.0f; row[65] = 0.0f; }
        }
        __syncthreads();

        // ---- Compute: each lane owns output x=lane, 16 consecutive co ----
        for (int ci_l = 0; ci_l < CI_BLK; ++ci_l) {
            const int ci = cb * CI_BLK + ci_l;
#pragma unroll
            for (int kz = 0; kz < 3; ++kz) {
#pragma unroll
                for (int ky = 0; ky < 3; ++ky) {
                    const int r = kz * 3 + ky;
                    const float* xrow = &lds[(size_t)(r * CI_BLK + ci_l) * 66 + lane];
                    const float xv0 = xrow[0];   // input x = lane-1
                    const float xv1 = xrow[1];   // input x = lane
                    const float xv2 = xrow[2];   // input x = lane+1
                    const float* wp = wbase + ci * 27 + kz * 9 + ky * 3;
#pragma unroll
                    for (int j = 0; j < 16; ++j) {
                        const float w0 = wp[(size_t)j * (CIN * 27) + 0];
                        const float w1 = wp[(size_t)j * (CIN * 27) + 1];
                        const float w2 = wp[(size_t)j * (CIN * 27) + 2];
                        acc[j] += w0 * xv0 + w1 * xv1 + w2 * xv2;
                    }
                }
            }
        }
    }

    // ---- Epilogue: +bias, x mask, dense write ----
    const float m = mask[(((size_t)b * DD + z) * DD + y) * DD + lane] ? 1.0f : 0.0f;
#pragma unroll
    for (int j = 0; j < 16; ++j) {
        const int co = co0 + j;
        const float v = (acc[j] + bias[co]) * m;
        out[((((size_t)b * COUT + co) * DD + z) * DD + y) * DD + lane] = v;
    }
}

extern "C" void kernel_launch(void* const* d_in, const int* in_sizes, int n_in,
                              void* d_out, int out_size, void* d_ws, size_t ws_size,
                              hipStream_t stream) {
    const float* xin  = (const float*)d_in[0];
    const int*   mask = (const int*)d_in[1];     // jnp.bool_ -> int32 per harness convention
    const float* w    = (const float*)d_in[2];
    const float* bias = (const float*)d_in[3];
    float*       out  = (float*)d_out;

    dim3 grid(DD, DD, 2);   // (y, z, b)
    dim3 block(256);
    sparse_conv3d_f32<<<grid, block, 0, stream>>>(xin, mask, w, bias, out);
}

// Round 3
// 106.957 us; speedup vs baseline: 34.8927x; 34.8927x over previous
//
#include <hip/hip_runtime.h>
#include <stdint.h>

// SparseConv3d bf16-MFMA implicit GEMM. B=2, Cin=32, Cout=64, D=64, K=3.
// Pipeline: pack_weights (fp32->bf16 A-fragment order, 110KB)
//           transpose_x  (fp32 NCDHW -> bf16 [b][z][y][x][ci], chunk-XOR-swizzled, 33.5MB)
//           conv_mfma    (block=(b,z,y-pair); 12 halo rows in LDS; mfma_f32_32x32x16_bf16)
// Swizzle: 16B chunk index c=ci>>3 stored at c ^ ((x>>1)&3) within each 64B x-row.
//   Baked into xt so LDS staging is a linear copy; ds_read_b128 B-frags are then
//   exactly 8 lanes/bank-group = conflict-free minimum.

#define DD 64
#define CIN 32
#define COUT 64

typedef __bf16 bf16x8 __attribute__((ext_vector_type(8)));
typedef float f32x16 __attribute__((ext_vector_type(16)));

#define XT_BYTES (2u * 64u * 64u * 64u * 32u * 2u)   // 33,554,432
#define WPK_U16  (27 * 2 * 2 * 64 * 8)               // 55,296 elems
#define WS_NEEDED (XT_BYTES + (size_t)WPK_U16 * 2)

__device__ __forceinline__ uint16_t f2bf(float f) {
    uint32_t u = __builtin_bit_cast(uint32_t, f);
    u += 0x7fffu + ((u >> 16) & 1u);   // RNE
    return (uint16_t)(u >> 16);
}

// ---------------- pre-kernel 1: weight pack ----------------
// wpk flat layout: (((k27*2 + cb)*2 + ct)*64 + lane)*8 + j
//   lane holds A[co = ct*32 + (lane&31)][ci = cb*16 + (lane>>5)*8 + j]
__global__ void pack_weights(const float* __restrict__ w, uint16_t* __restrict__ wpk) {
    int flat = blockIdx.x * 256 + threadIdx.x;
    if (flat >= WPK_U16) return;
    int j   = flat & 7;
    int l   = (flat >> 3) & 63;
    int ct  = (flat >> 9) & 1;
    int cb  = (flat >> 10) & 1;
    int k27 = flat >> 11;
    int co = ct * 32 + (l & 31);
    int ci = cb * 16 + ((l >> 5) * 8) + j;
    wpk[flat] = f2bf(w[(co * CIN + ci) * 27 + k27]);
}

// ---------------- pre-kernel 2: x transpose to channel-last bf16 ----------------
// xt row (b,z,y) = 4096B: elem (xv,ci) at uint16 pos xv*32 + ((ci>>3)^((xv>>1)&3))*8 + (ci&7)
__global__ __launch_bounds__(256)
void transpose_x(const float* __restrict__ x, uint16_t* __restrict__ xt) {
    __shared__ uint16_t tile[2048];
    const int y = blockIdx.x, z = blockIdx.y, b = blockIdx.z;
    const int t = threadIdx.x;
    const int ci = t >> 3;
    const int xs = (t & 7) * 8;
    const float* src = x + ((((size_t)b * CIN + ci) * DD + z) * DD + y) * DD + xs;
    float4 v0 = *(const float4*)src;
    float4 v1 = *(const float4*)(src + 4);
    float vals[8] = {v0.x, v0.y, v0.z, v0.w, v1.x, v1.y, v1.z, v1.w};
#pragma unroll
    for (int e = 0; e < 8; ++e) {
        int xv = xs + e;
        int pos = xv * 32 + (((ci >> 3) ^ ((xv >> 1) & 3)) << 3) + (ci & 7);
        tile[pos] = f2bf(vals[e]);
    }
    __syncthreads();
    uint16_t* dst = xt + (((size_t)b * DD + z) * DD + y) * 2048;
    ((uint4*)dst)[t] = ((const uint4*)tile)[t];
}

// ---------------- main kernel: conv via MFMA ----------------
__global__ __launch_bounds__(256, 3)
void conv_mfma(const uint16_t* __restrict__ xt, const uint16_t* __restrict__ wpk,
               const int* __restrict__ mask, const float* __restrict__ bias,
               float* __restrict__ out) {
    __shared__ __align__(16) unsigned char lds[12 * 4224];   // 50,688 B
    const int yp = blockIdx.x, z = blockIdx.y, b = blockIdx.z;
    const int y0 = yp * 2;
    const int tid = threadIdx.x;
    const int lane = tid & 63;
    const int w = tid >> 6;
    const int wy = w >> 1;   // which y row (0/1)
    const int wc = w & 1;    // which co half (0/1)

    // zero x-halo slots (12 rows x 2 ends x 64B)
    for (int i = tid; i < 96; i += 256) {
        int row = i >> 3, side = (i >> 2) & 1, k = i & 3;
        *(uint4*)&lds[row * 4224 + side * 4160 + k * 16] = make_uint4(0, 0, 0, 0);
    }
    // stage 12 rows (zz in z-1..z+1, yy in y0-1..y0+2), 4KB each, reg-staged
    for (int i = w; i < 48; i += 4) {
        int row = i >> 2, kc = i & 3;
        int zz = z - 1 + (row >> 2);
        int yy = y0 - 1 + (row & 3);
        unsigned ldsoff = row * 4224u + 64u + kc * 1024u + lane * 16u;
        if (zz >= 0 && zz < DD && yy >= 0 && yy < DD) {
            const uint16_t* src = xt + (((size_t)b * DD + zz) * DD + yy) * 2048 + kc * 512 + lane * 8;
            *(uint4*)&lds[ldsoff] = *(const uint4*)src;
        } else {
            *(uint4*)&lds[ldsoff] = make_uint4(0, 0, 0, 0);
        }
    }
    __syncthreads();

    const int u = lane & 31;
    const int h = lane >> 5;
    const int y = y0 + wy;

    f32x16 acc0, acc1;
#pragma unroll
    for (int i = 0; i < 16; ++i) { acc0[i] = 0.0f; acc1[i] = 0.0f; }

    for (int k27 = 0; k27 < 27; ++k27) {
        const int kz = k27 / 9;
        const int kyx = k27 % 9;
        const int ky = kyx / 3;
        const int kx = kyx % 3;
        const unsigned rowbase = (unsigned)(kz * 4 + wy + ky) * 4224u;
        const int xl0 = u + kx;         // LDS x slot, tile 0 (x = u + kx - 1)
        const int xl1 = 32 + u + kx;    // tile 1
        const unsigned s0 = (((unsigned)(xl0 - 1)) >> 1) & 3u;
        const unsigned s1 = (((unsigned)(xl1 - 1)) >> 1) & 3u;
#pragma unroll
        for (int cb = 0; cb < 2; ++cb) {
            bf16x8 av = *(const bf16x8*)(wpk + (size_t)((k27 * 2 + cb) * 2 + wc) * 512 + lane * 8);
            const unsigned chunk = (unsigned)(cb * 2 + h);
            bf16x8 bv0 = *(const bf16x8*)&lds[rowbase + xl0 * 64u + ((chunk ^ s0) << 4)];
            bf16x8 bv1 = *(const bf16x8*)&lds[rowbase + xl1 * 64u + ((chunk ^ s1) << 4)];
            acc0 = __builtin_amdgcn_mfma_f32_32x32x16_bf16(av, bv0, acc0, 0, 0, 0);
            acc1 = __builtin_amdgcn_mfma_f32_32x32x16_bf16(av, bv1, acc1, 0, 0, 0);
        }
    }

    // epilogue: +bias, x mask, store. C layout: col = lane&31, row = (r&3)+8*(r>>2)+4*h
    const size_t mbase = (((size_t)b * DD + z) * DD + y) * DD;
    const float m0 = mask[mbase + u] ? 1.0f : 0.0f;
    const float m1 = mask[mbase + 32 + u] ? 1.0f : 0.0f;
#pragma unroll
    for (int r = 0; r < 16; ++r) {
        int co = wc * 32 + (r & 3) + 8 * (r >> 2) + 4 * h;
        float bs = bias[co];
        size_t o = ((size_t)b * COUT + co) * (DD * DD * DD) + (size_t)z * (DD * DD) + (size_t)y * DD;
        out[o + u]      = (acc0[r] + bs) * m0;
        out[o + 32 + u] = (acc1[r] + bs) * m1;
    }
}

// ---------------- round-1 fp32 fallback (if ws too small) ----------------
#define CI_BLK 16
__global__ __launch_bounds__(256, 2)
void sparse_conv3d_f32(const float* __restrict__ x,
                       const int* __restrict__ mask,
                       const float* __restrict__ weight,
                       const float* __restrict__ bias,
                       float* __restrict__ out) {
    __shared__ float lds[9 * CI_BLK * 66];
    const int y = blockIdx.x, z = blockIdx.y, b = blockIdx.z;
    const int lane = threadIdx.x & 63;
    const int wave = __builtin_amdgcn_readfirstlane(threadIdx.x >> 6);
    float acc[16];
#pragma unroll
    for (int j = 0; j < 16; ++j) acc[j] = 0.0f;
    const int co0 = wave * 16;
    const float* wbase = weight + (size_t)co0 * (CIN * 27);
    for (int cb = 0; cb < 2; ++cb) {
        if (cb) __syncthreads();
        for (int i = wave; i < 9 * CI_BLK; i += 4) {
            const int r = i >> 4, ci_l = i & 15;
            const int zz = z + (r / 3) - 1, yy = y + (r % 3) - 1;
            const int ci = cb * CI_BLK + ci_l;
            float v = 0.0f;
            if (zz >= 0 && zz < DD && yy >= 0 && yy < DD)
                v = x[((((size_t)b * CIN + ci) * DD + zz) * DD + yy) * DD + lane];
            float* row = &lds[(size_t)i * 66];
            row[1 + lane] = v;
            if (lane == 0) { row[0] = 0.0f; row[65] = 0.0f; }
        }
        __syncthreads();
        for (int ci_l = 0; ci_l < CI_BLK; ++ci_l) {
            const int ci = cb * CI_BLK + ci_l;
#pragma unroll
            for (int kz = 0; kz < 3; ++kz) {
#pragma unroll
                for (int ky = 0; ky < 3; ++ky) {
                    const int r = kz * 3 + ky;
                    const float* xrow = &lds[(size_t)(r * CI_BLK + ci_l) * 66 + lane];
                    const float xv0 = xrow[0], xv1 = xrow[1], xv2 = xrow[2];
                    const float* wp = wbase + ci * 27 + kz * 9 + ky * 3;
#pragma unroll
                    for (int j = 0; j < 16; ++j) {
                        acc[j] += wp[(size_t)j * (CIN * 27) + 0] * xv0
                                + wp[(size_t)j * (CIN * 27) + 1] * xv1
                                + wp[(size_t)j * (CIN * 27) + 2] * xv2;
                    }
                }
            }
        }
    }
    const float m = mask[(((size_t)b * DD + z) * DD + y) * DD + lane] ? 1.0f : 0.0f;
#pragma unroll
    for (int j = 0; j < 16; ++j) {
        const int co = co0 + j;
        out[((((size_t)b * COUT + co) * DD + z) * DD + y) * DD + lane] = (acc[j] + bias[co]) * m;
    }
}

extern "C" void kernel_launch(void* const* d_in, const int* in_sizes, int n_in,
                              void* d_out, int out_size, void* d_ws, size_t ws_size,
                              hipStream_t stream) {
    const float* x    = (const float*)d_in[0];
    const int*   mask = (const int*)d_in[1];
    const float* w    = (const float*)d_in[2];
    const float* bias = (const float*)d_in[3];
    float*       out  = (float*)d_out;

    if (ws_size < WS_NEEDED) {
        // workspace too small for the MFMA path -- use the verified fp32 kernel
        sparse_conv3d_f32<<<dim3(DD, DD, 2), 256, 0, stream>>>(x, mask, w, bias, out);
        return;
    }

    uint16_t* xt  = (uint16_t*)d_ws;
    uint16_t* wpk = (uint16_t*)((char*)d_ws + XT_BYTES);

    pack_weights<<<(WPK_U16 + 255) / 256, 256, 0, stream>>>(w, wpk);
    transpose_x<<<dim3(DD, DD, 2), 256, 0, stream>>>(x, xt);
    conv_mfma<<<dim3(DD / 2, DD, 2), 256, 0, stream>>>(xt, wpk, mask, bias, out);
}